// Round 1
// baseline (23015.880 us; speedup 1.0000x reference)
//
#include <hip/hip_runtime.h>
#include <math.h>

#define T_STEPS 8192
#define I_DIM   64
#define H_DIM   2048
#define O_DIM   128
#define NBLK    256     // one block per CU; each owns 8 h-indices (32 gate rows)
#define NTHR    512     // 8 waves
#define NSLOT   4       // h slot ring depth
#define NAN_BITS 0x7FC00000u

typedef float v4f __attribute__((ext_vector_type(4)));

__device__ __forceinline__ float sigmoid_f(float x) {
    return 1.0f / (1.0f + __expf(-x));
}
__device__ __forceinline__ float tanh_fast(float x) {
    return 2.0f / (1.0f + __expf(-2.0f * x)) - 1.0f;
}

// DPP-based wave64 sum — VALU pipe, not LDS pipe. CTRL must be an immediate.
template <int CTRL>
__device__ __forceinline__ float dpp_add(float v) {
    int s = __builtin_amdgcn_update_dpp(0, __builtin_bit_cast(int, v),
                                        CTRL, 0xF, 0xF, true);
    return v + __builtin_bit_cast(float, s);
}
// After the sequence, lane 63 holds the full 64-lane sum.
__device__ __forceinline__ float wave_sum64_lane63(float v) {
    v = dpp_add<0x111>(v);  // row_shr:1
    v = dpp_add<0x112>(v);  // row_shr:2
    v = dpp_add<0x114>(v);  // row_shr:4
    v = dpp_add<0x118>(v);  // row_shr:8
    v = dpp_add<0x142>(v);  // row_bcast:15
    v = dpp_add<0x143>(v);  // row_bcast:31 -> lane63 = sum(0..63)
    return v;
}

__global__ void init_ws_kernel(unsigned int* Hbits) {
    int tid = blockIdx.x * blockDim.x + threadIdx.x;
    if (tid < NSLOT * H_DIM) {
        Hbits[tid] = (tid < H_DIM) ? 0u : NAN_BITS;
    }
}

// Persistent LSTM recurrence — round-7 fabric with two critical-path cuts:
//  (a) per-wave gate-complete decomposition: wave w computes rows
//      {q*2048 + cu*8 + w, q=0..3} (all four gates of ONE h-index), so the
//      DPP reduce lands i/f/g/o in lane 63 of the same wave. Elementwise +
//      cstate live in lane 63; NO gbuf, NO second __syncthreads, no 8x
//      replicated elementwise. Publish stays ONE coalesced 32B store from
//      wave 0 (131 MB WRITE_SIZE signature preserved — do NOT scatter),
//      gathered via an 8-word NaN-flag LDS buffer (parity double-buffered).
//  (b) poll-loop surgery: predicated reload (only words still NaN) +
//      adaptive backoff — sleep only while >=2 words missing; hot-spin the
//      single-straggler tail (tail traffic ~32B/CU/pass, congestion-safe).
//  x-part dot computed from previous-step-staged xbuf while poll loads fly.
// hbuf/xbuf parity double-buffered => the single remaining barrier per step
// is sufficient (a wave staging step t passed barrier(t-1), which implies
// every wave finished its step t-2 dot on the same-parity buffer).
__global__ __launch_bounds__(NTHR, 2) void lstm_persistent(
    const float* __restrict__ x,     // [T, 64]
    const float* __restrict__ Wih,   // [8192, 64]
    const float* __restrict__ Whh,   // [8192, 2048]
    const float* __restrict__ bih,   // [8192]
    const float* __restrict__ bhh,   // [8192]
    unsigned int* __restrict__ Hbits)// [NSLOT][2048] in ws (float bits)
{
    const int cu   = blockIdx.x;
    const int tid  = threadIdx.x;
    const int w    = tid >> 6;
    const int lane = tid & 63;
    const int hj   = cu * 8 + w;     // this wave's h-index

    __shared__ float        hbuf[2][H_DIM];   // 16 KB, parity double-buffer
    __shared__ float        xbuf[2][I_DIM];
    __shared__ unsigned int houtb[2][8];      // per-step h gather, NaN-flagged

    // ---- one-time: W_hh fragment into registers (unified VGPR/AGPR file) ----
    // wreg[q][m] = Whh[q*2048 + hj][m*256 + lane*4 .. +3]
    v4f wreg[4][8];
#pragma unroll
    for (int q = 0; q < 4; q++) {
        const float* p = Whh + (size_t)(q * H_DIM + hj) * H_DIM + lane * 4;
#pragma unroll
        for (int m = 0; m < 8; m++)
            wreg[q][m] = *(const v4f*)(p + m * 256);
    }
    // x-part: lane covers gate q=lane>>4 of row hj, k-range (lane&15)*4..+4
    float xw[4];
    {
        const int r = (lane >> 4) * H_DIM + hj;
        const float* p = Wih + (size_t)r * I_DIM + (lane & 15) * 4;
#pragma unroll
        for (int m = 0; m < 4; m++) xw[m] = p[m];
    }
    const float bias0 = bih[0 * H_DIM + hj] + bhh[0 * H_DIM + hj];
    const float bias1 = bih[1 * H_DIM + hj] + bhh[1 * H_DIM + hj];
    const float bias2 = bih[2 * H_DIM + hj] + bhh[2 * H_DIM + hj];
    const float bias3 = bih[3 * H_DIM + hj] + bhh[3 * H_DIM + hj];
    float cstate = 0.0f;   // lives in lane 63 of each wave

    if (tid < 16) houtb[tid >> 3][tid & 7] = NAN_BITS;
    if (tid < I_DIM) xbuf[0][tid] = x[tid];
    __syncthreads();

    for (int t = 0; t < T_STEPS; t++) {
        const int par    = t & 1;
        const int slot_r = t & (NSLOT - 1);
        const int slot_w = (t + 1) & (NSLOT - 1);
        const int slot_z = (t + 2) & (NSLOT - 1);
        const unsigned int* Hr = Hbits + slot_r * H_DIM;

        // ---- 1. issue poll batch ASAP (4 independent LLC loads in flight) ----
        unsigned int u0 = __hip_atomic_load(Hr + tid,        __ATOMIC_RELAXED, __HIP_MEMORY_SCOPE_AGENT);
        unsigned int u1 = __hip_atomic_load(Hr + tid + 512,  __ATOMIC_RELAXED, __HIP_MEMORY_SCOPE_AGENT);
        unsigned int u2 = __hip_atomic_load(Hr + tid + 1024, __ATOMIC_RELAXED, __HIP_MEMORY_SCOPE_AGENT);
        unsigned int u3 = __hip_atomic_load(Hr + tid + 1536, __ATOMIC_RELAXED, __HIP_MEMORY_SCOPE_AGENT);

        // next-step x load issued early (independent)
        float xv_next = 0.0f;
        if (tid < I_DIM && t + 1 < T_STEPS)
            xv_next = x[(size_t)(t + 1) * I_DIM + tid];

        // x-part dot for THIS step from xbuf staged last step — VALU work that
        // hides under the poll-load latency (no dependence on u0..u3).
        float xp = 0.0f;
        {
            const float* xb = xbuf[par];
            const int b = (lane & 15) * 4;
#pragma unroll
            for (int m = 0; m < 4; m++) xp += xw[m] * xb[b + m];
        }

        // ---- 2. adaptive predicated spin ----
        // sleep only while >=2 words missing (early-phase congestion control);
        // hot-spin the single-straggler tail; reload ONLY missing words.
        for (;;) {
            const bool m0 = (u0 == NAN_BITS), m1 = (u1 == NAN_BITS);
            const bool m2 = (u2 == NAN_BITS), m3 = (u3 == NAN_BITS);
            if (!(m0 | m1 | m2 | m3)) break;
            const int nm = (int)m0 + (int)m1 + (int)m2 + (int)m3;
            if (nm > 1) __builtin_amdgcn_s_sleep(2);
            if (m0) u0 = __hip_atomic_load(Hr + tid,        __ATOMIC_RELAXED, __HIP_MEMORY_SCOPE_AGENT);
            if (m1) u1 = __hip_atomic_load(Hr + tid + 512,  __ATOMIC_RELAXED, __HIP_MEMORY_SCOPE_AGENT);
            if (m2) u2 = __hip_atomic_load(Hr + tid + 1024, __ATOMIC_RELAXED, __HIP_MEMORY_SCOPE_AGENT);
            if (m3) u3 = __hip_atomic_load(Hr + tid + 1536, __ATOMIC_RELAXED, __HIP_MEMORY_SCOPE_AGENT);
        }
        hbuf[par][tid]        = __uint_as_float(u0);
        hbuf[par][tid + 512]  = __uint_as_float(u1);
        hbuf[par][tid + 1024] = __uint_as_float(u2);
        hbuf[par][tid + 1536] = __uint_as_float(u3);
        if (tid < I_DIM && t + 1 < T_STEPS) xbuf[par ^ 1][tid] = xv_next;
        // reset own chunk 2 slots ahead (holds h_{t-2}, fully consumed).
        if (w == 0 && lane < 8) {
            __hip_atomic_store(Hbits + slot_z * H_DIM + cu * 8 + lane, NAN_BITS,
                               __ATOMIC_RELAXED, __HIP_MEMORY_SCOPE_AGENT);
        }
        __syncthreads();   // the ONLY barrier per step

        // ---- 3. dot: 4 gate rows of h-index hj, 8 x (ds_read_b128 + v4f FMA) ----
        v4f av0 = {0.f,0.f,0.f,0.f}, av1 = {0.f,0.f,0.f,0.f};
        v4f av2 = {0.f,0.f,0.f,0.f}, av3 = {0.f,0.f,0.f,0.f};
#pragma unroll
        for (int m = 0; m < 8; m++) {
            v4f hv = *(const v4f*)&hbuf[par][m * 256 + lane * 4];
            av0 += wreg[0][m] * hv;
            av1 += wreg[1][m] * hv;
            av2 += wreg[2][m] * hv;
            av3 += wreg[3][m] * hv;
        }
        float acc0 = (av0[0] + av0[1]) + (av0[2] + av0[3]);
        float acc1 = (av1[0] + av1[1]) + (av1[2] + av1[3]);
        float acc2 = (av2[0] + av2[1]) + (av2[2] + av2[3]);
        float acc3 = (av3[0] + av3[1]) + (av3[2] + av3[3]);
        {   // fold in W_ih * x_t : lane's xp belongs to gate sel=lane>>4
            const int sel = lane >> 4;
            acc0 += (sel == 0) ? xp : 0.0f;
            acc1 += (sel == 1) ? xp : 0.0f;
            acc2 += (sel == 2) ? xp : 0.0f;
            acc3 += (sel == 3) ? xp : 0.0f;
        }
        // ---- 4. DPP reduction; all four gates land in lane 63 of this wave ----
        acc0 = wave_sum64_lane63(acc0);
        acc1 = wave_sum64_lane63(acc1);
        acc2 = wave_sum64_lane63(acc2);
        acc3 = wave_sum64_lane63(acc3);

        // ---- 5. elementwise in lane 63 only; publish via LDS NaN-flag gather ----
        if (lane == 63) {
            float iv = sigmoid_f(acc0 + bias0);
            float fv = sigmoid_f(acc1 + bias1);
            float gv = tanh_fast(acc2 + bias2);
            float ov = sigmoid_f(acc3 + bias3);
            cstate = fv * cstate + iv * gv;
            float hval = ov * tanh_fast(cstate);
            __hip_atomic_store(&houtb[par][w], __float_as_uint(hval),
                               __ATOMIC_RELAXED, __HIP_MEMORY_SCOPE_WORKGROUP);
        }
        // wave 0 gathers the 8 values (LDS spin) and publishes ONE coalesced
        // 32B agent store — the ready flag for every consumer.
        if (w == 0 && lane < 8) {
            unsigned int hb;
            do {
                hb = __hip_atomic_load(&houtb[par][lane],
                                       __ATOMIC_RELAXED, __HIP_MEMORY_SCOPE_WORKGROUP);
            } while (hb == NAN_BITS);
            __hip_atomic_store(Hbits + slot_w * H_DIM + cu * 8 + lane, hb,
                               __ATOMIC_RELAXED, __HIP_MEMORY_SCOPE_AGENT);
            // re-arm the LDS flag for step t+2 (same parity); safe: next write
            // to houtb[par] is by waves past barrier(t+2) > this point.
            __hip_atomic_store(&houtb[par][lane], NAN_BITS,
                               __ATOMIC_RELAXED, __HIP_MEMORY_SCOPE_WORKGROUP);
        }
        // other waves run straight into step t+1's poll (early start).
    }
}

// Final linear: out[o] = h_T . W_lin[o,:] + b_lin[o].  One wave per output.
// h_T lives in slot (T & 3) == 0.
__global__ void final_linear(const float* __restrict__ hT,
                             const float* __restrict__ Wlin,
                             const float* __restrict__ blin,
                             float* __restrict__ out)
{
    int gw   = (blockIdx.x * blockDim.x + threadIdx.x) >> 6;
    int lane = threadIdx.x & 63;
    if (gw < O_DIM) {
        const float* wp = Wlin + (size_t)gw * H_DIM;
        float s = 0.f;
        for (int k = lane; k < H_DIM; k += 64)
            s += wp[k] * hT[k];
#pragma unroll
        for (int off = 32; off; off >>= 1) s += __shfl_xor(s, off, 64);
        if (lane == 0) out[gw] = s + blin[gw];
    }
}

extern "C" void kernel_launch(void* const* d_in, const int* in_sizes, int n_in,
                              void* d_out, int out_size, void* d_ws, size_t ws_size,
                              hipStream_t stream)
{
    const float* x    = (const float*)d_in[0];
    const float* Wih  = (const float*)d_in[1];
    const float* Whh  = (const float*)d_in[2];
    const float* bih  = (const float*)d_in[3];
    const float* bhh  = (const float*)d_in[4];
    const float* Wlin = (const float*)d_in[5];
    const float* blin = (const float*)d_in[6];
    float* out = (float*)d_out;

    unsigned int* Hbits = (unsigned int*)d_ws;

    hipLaunchKernelGGL(init_ws_kernel, dim3((NSLOT * H_DIM + 255) / 256), dim3(256),
                       0, stream, Hbits);

    void* args[] = { (void*)&x, (void*)&Wih, (void*)&Whh, (void*)&bih, (void*)&bhh,
                     (void*)&Hbits };
    (void)hipLaunchCooperativeKernel(reinterpret_cast<void*>(lstm_persistent),
                                     dim3(NBLK), dim3(NTHR), args, 0, stream);

    // h_T is in slot (T_STEPS & 3) == 0
    hipLaunchKernelGGL(final_linear, dim3(32), dim3(256), 0, stream,
                       (const float*)Hbits, Wlin, blin, out);
}

// Round 2
// 22345.454 us; speedup vs baseline: 1.0300x; 1.0300x over previous
//
#include <hip/hip_runtime.h>
#include <math.h>

#define T_STEPS 8192
#define I_DIM   64
#define H_DIM   2048
#define O_DIM   128
#define NBLK    256     // one block per CU; each owns 8 h-indices (32 gate rows)
#define NTHR    512     // 8 waves
#define NSLOT   4       // h slot ring depth
#define NAN_BITS 0x7FC00000u

typedef float v4f __attribute__((ext_vector_type(4)));
typedef unsigned int u32x4 __attribute__((ext_vector_type(4)));

// ws layout: float Hbuf[NSLOT][2048]
__device__ __forceinline__ float sigmoid_f(float x) {
    return 1.0f / (1.0f + __expf(-x));
}
__device__ __forceinline__ float tanh_fast(float x) {
    // 2*sigmoid(2x)-1; saturates correctly for |x| large
    return 2.0f / (1.0f + __expf(-2.0f * x)) - 1.0f;
}

// One 16B coherent poll load. sc1 = agent-scope (same bits hipcc emits for
// __hip_atomic_load relaxed/agent, which the proven round-0 fabric used at
// 4B width). Word-level data-as-flag needs no 16B atomicity: each 4B word is
// independently either NAN_BITS or the final published value.
__device__ __forceinline__ u32x4 llc_load16(const unsigned int* p) {
    u32x4 r;
    asm volatile("global_load_dwordx4 %0, %1, off sc1\n\t"
                 "s_waitcnt vmcnt(0)"
                 : "=v"(r) : "v"(p) : "memory");
    return r;
}

// DPP-based wave64 sum — VALU pipe, NOT the LDS pipe (__shfl_xor = ds_bpermute
// burns ~1150 cy/step/CU of LDS throughput at 8 waves; DPP adds are VALU).
// CTRL must be an immediate -> template parameter.
template <int CTRL>
__device__ __forceinline__ float dpp_add(float v) {
    int s = __builtin_amdgcn_update_dpp(0, __builtin_bit_cast(int, v),
                                        CTRL, 0xF, 0xF, true);
    return v + __builtin_bit_cast(float, s);
}
// After the sequence, lane 63 holds the full 64-lane sum.
__device__ __forceinline__ float wave_sum64_lane63(float v) {
    v = dpp_add<0x111>(v);  // row_shr:1
    v = dpp_add<0x112>(v);  // row_shr:2
    v = dpp_add<0x114>(v);  // row_shr:4
    v = dpp_add<0x118>(v);  // row_shr:8   -> lane15 of each row16 = row-partial
    v = dpp_add<0x142>(v);  // row_bcast:15 -> lane31 = sum(0..31), l63 = sum(32..63)
    v = dpp_add<0x143>(v);  // row_bcast:31 -> lane63 = sum(0..63)
    return v;
}

__global__ void init_ws_kernel(unsigned int* Hbits) {
    int tid = blockIdx.x * blockDim.x + threadIdx.x;
    if (tid < NSLOT * H_DIM) {
        // slot 0 = h_0 = 0.0f; slots 1..3 = NaN sentinel ("not ready")
        Hbits[tid] = (tid < H_DIM) ? 0u : NAN_BITS;
    }
}

// Persistent LSTM recurrence — the proven round-0 fabric (19.16 ms) with ONE
// change: 16B polling. Thread tid now owns the contiguous words tid*4..tid*4+3
// (instead of strided tid + k*512) and polls them with a single
// global_load_dwordx4 sc1 per pass — 4x fewer coherence-fabric requests at
// identical sleep(2) cadence. Staging becomes one ds_write_b128. Everything
// else (two barriers, gbuf, replicated elementwise, single coalesced 32B
// publish and reset from wave 0) is verbatim round-0 — round-1's hot-spin +
// LDS-gather publish regressed (FETCH +70%, congestion collapse outliers).
// Wave w: gate q = w>>1, joff = (w&1)*4; rows = q*2048 + cu*8 + joff + i
// Dot k-mapping: lane l covers k = m*256 + l*4 + j -> one ds_read_b128 per m.
__global__ __launch_bounds__(NTHR, 2) void lstm_persistent(
    const float* __restrict__ x,     // [T, 64]
    const float* __restrict__ Wih,   // [8192, 64]
    const float* __restrict__ Whh,   // [8192, 2048]
    const float* __restrict__ bih,   // [8192]
    const float* __restrict__ bhh,   // [8192]
    unsigned int* __restrict__ Hbits)// [NSLOT][2048] in ws (float bits)
{
    const int cu   = blockIdx.x;
    const int tid  = threadIdx.x;
    const int w    = tid >> 6;
    const int lane = tid & 63;

    __shared__ float hbuf[H_DIM];   // 8 KB, layout hbuf[k] = h[k]
    __shared__ float xbuf[I_DIM];
    __shared__ float gbuf[32];      // gbuf[g*8 + j] = pre-activation of gate g, h-sub j

    const int q    = w >> 1;
    const int joff = (w & 1) * 4;
    const int row0 = q * H_DIM + cu * 8 + joff;

    // ---- one-time: W_hh fragment into registers (unified VGPR/AGPR file) ----
    // wreg[i][m] = W[row0+i][m*256 + lane*4 .. +3]   (coalesced 16B loads)
    v4f wreg[4][8];
#pragma unroll
    for (int i = 0; i < 4; i++) {
        const float* p = Whh + (size_t)(row0 + i) * H_DIM + lane * 4;
#pragma unroll
        for (int m = 0; m < 8; m++)
            wreg[i][m] = *(const v4f*)(p + m * 256);
    }
    // x-part: lane handles row (row0 + (lane>>4)), k-range (lane&15)*4 .. +4
    float xw[4];
    {
        const int xr = row0 + (lane >> 4);
        const float* p = Wih + (size_t)xr * I_DIM + (lane & 15) * 4;
#pragma unroll
        for (int m = 0; m < 4; m++) xw[m] = p[m];
    }
    // biases: every wave keeps them (elementwise phase is replicated per wave)
    float bias[4] = {0.f, 0.f, 0.f, 0.f};
    if (lane < 8) {
#pragma unroll
        for (int g = 0; g < 4; g++) {
            int r = g * H_DIM + cu * 8 + lane;
            bias[g] = bih[r] + bhh[r];
        }
    }
    float cstate = 0.0f;   // replicated in lanes 0..7 of every wave

    for (int t = 0; t < T_STEPS; t++) {
        const int slot_r = t & (NSLOT - 1);
        const int slot_w = (t + 1) & (NSLOT - 1);
        const int slot_z = (t + 2) & (NSLOT - 1);

        // hoist the independent x load above the spin
        float xv_own = (tid < I_DIM) ? x[(size_t)t * I_DIM + tid] : 0.0f;

        // ---- 1. poll h_t (data-as-flag) and stage into LDS ----
        // One 16B sc1 load per pass; s_sleep(2) backoff on EVERY failed pass
        // (round 6: FETCH -35%, dur -9%; round-1 hot-spin variant collapsed).
        {
            const unsigned int* Hr = Hbits + slot_r * H_DIM + tid * 4;
            u32x4 u;
            for (;;) {
                u = llc_load16(Hr);
                bool miss = (u.x == NAN_BITS) | (u.y == NAN_BITS) |
                            (u.z == NAN_BITS) | (u.w == NAN_BITS);
                if (!miss) break;
                __builtin_amdgcn_s_sleep(2);
            }
            v4f hv4 = { __uint_as_float(u.x), __uint_as_float(u.y),
                        __uint_as_float(u.z), __uint_as_float(u.w) };
            *(v4f*)&hbuf[tid * 4] = hv4;   // one ds_write_b128
            if (tid < I_DIM) xbuf[tid] = xv_own;
        }
        // reset own chunk 2 slots ahead (holds h_{t-2}, fully consumed, skew<=1).
        // Coalesced: 8 lanes of wave 0, one 32B transaction.
        if (w == 0 && lane < 8) {
            __hip_atomic_store(Hbits + slot_z * H_DIM + cu * 8 + lane, NAN_BITS,
                               __ATOMIC_RELAXED, __HIP_MEMORY_SCOPE_AGENT);
        }
        __syncthreads();

        // ---- 2. dot products: 4 rows per wave, 8 x (ds_read_b128 + packed FMA) ----
        v4f av0 = {0.f,0.f,0.f,0.f}, av1 = {0.f,0.f,0.f,0.f};
        v4f av2 = {0.f,0.f,0.f,0.f}, av3 = {0.f,0.f,0.f,0.f};
#pragma unroll
        for (int m = 0; m < 8; m++) {
            v4f hv = *(const v4f*)&hbuf[m * 256 + lane * 4];
            av0 += wreg[0][m] * hv;
            av1 += wreg[1][m] * hv;
            av2 += wreg[2][m] * hv;
            av3 += wreg[3][m] * hv;
        }
        float acc0 = (av0[0] + av0[1]) + (av0[2] + av0[3]);
        float acc1 = (av1[0] + av1[1]) + (av1[2] + av1[3]);
        float acc2 = (av2[0] + av2[1]) + (av2[2] + av2[3]);
        float acc3 = (av3[0] + av3[1]) + (av3[2] + av3[3]);
        {   // fold in W_ih * x_t
            float xp = 0.f;
            const int b = (lane & 15) * 4;
#pragma unroll
            for (int m = 0; m < 4; m++) xp += xw[m] * xbuf[b + m];
            const int sel = lane >> 4;
            acc0 += (sel == 0) ? xp : 0.0f;
            acc1 += (sel == 1) ? xp : 0.0f;
            acc2 += (sel == 2) ? xp : 0.0f;
            acc3 += (sel == 3) ? xp : 0.0f;
        }
        // ---- 3. DPP reduction (VALU pipe); totals land in lane 63 ----
        acc0 = wave_sum64_lane63(acc0);
        acc1 = wave_sum64_lane63(acc1);
        acc2 = wave_sum64_lane63(acc2);
        acc3 = wave_sum64_lane63(acc3);
        if (lane == 63) {
            gbuf[q * 8 + joff + 0] = acc0;
            gbuf[q * 8 + joff + 1] = acc1;
            gbuf[q * 8 + joff + 2] = acc2;
            gbuf[q * 8 + joff + 3] = acc3;
        }
        __syncthreads();

        // ---- 4. elementwise cell update, replicated in every wave (lanes 0..7);
        //         wave 0 publishes — ONE coalesced 32B store = the ready flag ----
        if (lane < 8) {
            float gi = gbuf[0 * 8 + lane] + bias[0];
            float gf = gbuf[1 * 8 + lane] + bias[1];
            float gg = gbuf[2 * 8 + lane] + bias[2];
            float go = gbuf[3 * 8 + lane] + bias[3];
            float iv = sigmoid_f(gi);
            float fv = sigmoid_f(gf);
            float gv = tanh_fast(gg);
            float ov = sigmoid_f(go);
            cstate = fv * cstate + iv * gv;
            float hval = ov * tanh_fast(cstate);
            if (w == 0) {
                __hip_atomic_store(Hbits + slot_w * H_DIM + cu * 8 + lane,
                                   __float_as_uint(hval),
                                   __ATOMIC_RELAXED, __HIP_MEMORY_SCOPE_AGENT);
            }
        }
        // next iteration's poll phase touches only Hbits/hbuf/xbuf; gbuf reuse
        // is protected by the next iteration's first __syncthreads.
    }
}

// Final linear: out[o] = h_T . W_lin[o,:] + b_lin[o].  One wave per output.
// h_T lives in slot (T & 3) == 0.
__global__ void final_linear(const float* __restrict__ hT,
                             const float* __restrict__ Wlin,
                             const float* __restrict__ blin,
                             float* __restrict__ out)
{
    int gw   = (blockIdx.x * blockDim.x + threadIdx.x) >> 6;
    int lane = threadIdx.x & 63;
    if (gw < O_DIM) {
        const float* wp = Wlin + (size_t)gw * H_DIM;
        float s = 0.f;
        for (int k = lane; k < H_DIM; k += 64)
            s += wp[k] * hT[k];
#pragma unroll
        for (int off = 32; off; off >>= 1) s += __shfl_xor(s, off, 64);
        if (lane == 0) out[gw] = s + blin[gw];
    }
}

extern "C" void kernel_launch(void* const* d_in, const int* in_sizes, int n_in,
                              void* d_out, int out_size, void* d_ws, size_t ws_size,
                              hipStream_t stream)
{
    const float* x    = (const float*)d_in[0];
    const float* Wih  = (const float*)d_in[1];
    const float* Whh  = (const float*)d_in[2];
    const float* bih  = (const float*)d_in[3];
    const float* bhh  = (const float*)d_in[4];
    const float* Wlin = (const float*)d_in[5];
    const float* blin = (const float*)d_in[6];
    float* out = (float*)d_out;

    unsigned int* Hbits = (unsigned int*)d_ws;

    hipLaunchKernelGGL(init_ws_kernel, dim3((NSLOT * H_DIM + 255) / 256), dim3(256),
                       0, stream, Hbits);

    void* args[] = { (void*)&x, (void*)&Wih, (void*)&Whh, (void*)&bih, (void*)&bhh,
                     (void*)&Hbits };
    (void)hipLaunchCooperativeKernel(reinterpret_cast<void*>(lstm_persistent),
                                     dim3(NBLK), dim3(NTHR), args, 0, stream);

    // h_T is in slot (T_STEPS & 3) == 0
    hipLaunchKernelGGL(final_linear, dim3(32), dim3(256), 0, stream,
                       (const float*)Hbits, Wlin, blin, out);
}